// Round 4
// baseline (433.992 us; speedup 1.0000x reference)
//
#include <hip/hip_runtime.h>
#include <stdint.h>

#define B  32
#define KK 8
#define LQ 128
#define LR 256
#define H  512
#define LL 2176   // LQ + KK*LR
#define STRIDE 40 // LDS row stride (k1 only)

typedef short s16x8 __attribute__((ext_vector_type(8)));
typedef float f32x4 __attribute__((ext_vector_type(4)));

__device__ __forceinline__ unsigned short f2bf(float f) {
    unsigned int u = __float_as_uint(f);
    unsigned int r = (u + 0x7FFFu + ((u >> 16) & 1u)) >> 16;
    return (unsigned short)r;
}
__device__ __forceinline__ float bf2f(unsigned short h) {
    return __uint_as_float(((unsigned int)h) << 16);
}
__device__ __forceinline__ void gload16(const unsigned short* g, unsigned short* l) {
    __builtin_amdgcn_global_load_lds(
        (const __attribute__((address_space(1))) void*)g,
        (__attribute__((address_space(3))) void*)l, 16, 0, 0);
}
__device__ __forceinline__ float fexp2(float x) {
#if __has_builtin(__builtin_amdgcn_exp2f)
    return __builtin_amdgcn_exp2f(x);
#else
    return __expf(x * 0.69314718056f);
#endif
}
__device__ __forceinline__ float frcp(float x) {
#if __has_builtin(__builtin_amdgcn_rcpf)
    return __builtin_amdgcn_rcpf(x);
#else
    return 1.f / x;
#endif
}
// tanh(x) = 1 - 2/(1+e^{2x}); saturates correctly via exp2/rcp HW ops
__device__ __forceinline__ float fast_tanh(float x) {
    float e = fexp2(x * 2.885390082f);
    return 1.f - 2.f * frcp(1.f + e);
}
#define LOG2E 1.4426950408889634f

// ---------------------------------------------------------------- K0: fp32->bf16 + zero-init + sWs
// blocks < 2048: grid-stride convert/zero; blocks >= 2048: sWs matvec (input-only).
#define NQ4 (B * LQ * H / 4)        // 524288
#define NR4 (B * KK * LR * H / 4)   // 8388608
#define NW4 (H * H / 4)             // 65536
#define NL4 (B * LL / 4)            // 17408
#define NC4 (B * H / 4)             // 4096
#define NTOT4 (NQ4 + NR4 + 2 * NW4 + NL4 + NC4)
#define K0GRID 2048
__global__ __launch_bounds__(256) void k0_convert(
    const float* __restrict__ h_q, const float* __restrict__ h_r,
    const float* __restrict__ U_w, const float* __restrict__ Wqr_w,
    unsigned short* __restrict__ Xb, unsigned short* __restrict__ Uwb,
    unsigned short* __restrict__ Wqrb, float* __restrict__ logits,
    float* __restrict__ out_ct, const float* __restrict__ s_t,
    const float* __restrict__ Ws_w, float* __restrict__ sWs) {
    int t = threadIdx.x;
    if (blockIdx.x >= K0GRID) {
        // sWs: 256 blocks, (b, oc)
        int idx = blockIdx.x - K0GRID;
        int b = idx >> 3, oc = idx & 7;
        __shared__ __align__(16) float sl[H];
        for (int i = t; i < H; i += 256) sl[i] = s_t[b * H + i];
        __syncthreads();
        int o = oc * 64 + (t >> 2);
        int part = t & 3;
        const float4* sl4 = (const float4*)sl;
        const float4* wr4 = (const float4*)(Ws_w + (size_t)o * H);
        float a = 0.f;
        for (int i = part * 32; i < part * 32 + 32; ++i) {
            float4 x = sl4[i], y = wr4[i];
            a += x.x * y.x + x.y * y.y + x.z * y.z + x.w * y.w;
        }
        a += __shfl_xor(a, 1);
        a += __shfl_xor(a, 2);
        if (part == 0) sWs[b * H + o] = a;
        return;
    }
    for (unsigned int u = blockIdx.x * 256 + t; u < NTOT4; u += K0GRID * 256) {
        if (u < NQ4 + NR4) {
            const float* src; unsigned short* dst;
            if (u < NQ4) {
                unsigned int f = u * 4;
                unsigned int b = f >> 16, rem = f & 65535u;  // LQ*H = 65536
                src = h_q + f;
                dst = Xb + (size_t)b * (LL * H) + rem;
            } else {
                unsigned int f = (u - NQ4) * 4;
                unsigned int b = f >> 20, rem = f & 1048575u; // KK*LR*H = 1048576
                src = h_r + f;
                dst = Xb + (size_t)b * (LL * H) + LQ * H + rem;
            }
            float4 v = *(const float4*)src;
            ushort4 o;
            o.x = f2bf(v.x); o.y = f2bf(v.y); o.z = f2bf(v.z); o.w = f2bf(v.w);
            *(ushort4*)dst = o;
        } else if (u < NQ4 + NR4 + 2 * NW4) {
            unsigned int v4 = u - (NQ4 + NR4);
            const float* src = (v4 < NW4) ? (U_w + v4 * 4) : (Wqr_w + (v4 - NW4) * 4);
            unsigned short* dst = (v4 < NW4) ? (Uwb + v4 * 4) : (Wqrb + (v4 - NW4) * 4);
            float4 v = *(const float4*)src;
            ushort4 o;
            o.x = f2bf(v.x); o.y = f2bf(v.y); o.z = f2bf(v.z); o.w = f2bf(v.w);
            *(ushort4*)dst = o;
        } else {
            unsigned int z = u - (NQ4 + NR4 + 2 * NW4);
            float4 zero = {0.f, 0.f, 0.f, 0.f};
            if (z < NL4) *(float4*)(logits + z * 4) = zero;
            else *(float4*)(out_ct + (z - NL4) * 4) = zero;
        }
    }
}

// ---------------------------------------------------------------- K1: hqU = Xq @ Uw^T (bf16)
__global__ __launch_bounds__(256) void k1_gemm_hqU(
    const unsigned short* __restrict__ Xb, const unsigned short* __restrict__ Uwb,
    unsigned short* __restrict__ hqU) {
    __shared__ __align__(16) unsigned short As[64 * STRIDE];
    __shared__ __align__(16) unsigned short Bs[64 * STRIDE];
    int tid = threadIdx.x;
    int wave = tid >> 6, lane = tid & 63;
    int quad = lane >> 4, l16 = lane & 15;
    int wr = wave >> 1, wc = wave & 1;
    int m0 = blockIdx.x * 64, n0 = blockIdx.y * 64;

    f32x4 acc[2][2] = {};
    int srow = tid >> 2, sk8 = tid & 3;
    int am = m0 + srow;
    size_t arow = (size_t)(am >> 7) * LL + (am & 127);
    for (int k0 = 0; k0 < H; k0 += 32) {
        *(uint4*)&As[srow * STRIDE + sk8 * 8] =
            *(const uint4*)(Xb + arow * H + k0 + sk8 * 8);
        *(uint4*)&Bs[srow * STRIDE + sk8 * 8] =
            *(const uint4*)(Uwb + (size_t)(n0 + srow) * H + k0 + sk8 * 8);
        __syncthreads();
        s16x8 af[2], bfr[2];
#pragma unroll
        for (int mi = 0; mi < 2; ++mi)
            af[mi] = *(const s16x8*)&As[(wr * 32 + mi * 16 + l16) * STRIDE + quad * 8];
#pragma unroll
        for (int ni = 0; ni < 2; ++ni)
            bfr[ni] = *(const s16x8*)&Bs[(wc * 32 + ni * 16 + l16) * STRIDE + quad * 8];
#pragma unroll
        for (int mi = 0; mi < 2; ++mi)
#pragma unroll
            for (int ni = 0; ni < 2; ++ni)
                acc[mi][ni] = __builtin_amdgcn_mfma_f32_16x16x32_bf16(
                    af[mi], bfr[ni], acc[mi][ni], 0, 0, 0);
        __syncthreads();
    }
#pragma unroll
    for (int mi = 0; mi < 2; ++mi)
#pragma unroll
        for (int ni = 0; ni < 2; ++ni)
#pragma unroll
            for (int i = 0; i < 4; ++i) {
                int row = m0 + wr * 32 + mi * 16 + quad * 4 + i;
                int col = n0 + wc * 32 + ni * 16 + l16;
                hqU[(size_t)row * H + col] = f2bf(acc[mi][ni][i]);
            }
}

// ---------------------------------------------------------------- K2: score maxes (glds+swizzle)
__global__ __launch_bounds__(256) void k2_scores(
    const unsigned short* __restrict__ hqU, const unsigned short* __restrict__ Xb,
    float* __restrict__ maxq_part, float* __restrict__ maxr_part) {
    __shared__ __align__(16) unsigned short As[64 * 64];
    __shared__ __align__(16) unsigned short Bs[128 * 64];
    __shared__ float redA[64 * 2];
    __shared__ float redB[128 * 2];
    int idx = blockIdx.x;
    int rt = idx & 1, qt = (idx >> 1) & 1, k = (idx >> 2) & 7, b = idx >> 5;
    int tid = threadIdx.x;
    int wave = tid >> 6, lane = tid & 63;
    int quad = lane >> 4, l16 = lane & 15;
    int wr = wave >> 1, wc = wave & 1;

    const unsigned short* Ab = hqU + (size_t)(b * LQ + qt * 64) * H;
    const unsigned short* Bb = Xb + (size_t)(b * LL + LQ + k * LR + rt * 128) * H;

    const unsigned short* ag[2]; unsigned short* la[2];
    const unsigned short* bg[4]; unsigned short* lb[4];
#pragma unroll
    for (int i = 0; i < 2; ++i) {
        int g = (wave * 2 + i) * 64 + lane;
        int r = g >> 3, c = g & 7, cs = c ^ (r & 7);
        ag[i] = Ab + (size_t)r * H + cs * 8;
        la[i] = As + (wave * 2 + i) * 512;
    }
#pragma unroll
    for (int i = 0; i < 4; ++i) {
        int g = (wave * 4 + i) * 64 + lane;
        int r = g >> 3, c = g & 7, cs = c ^ (r & 7);
        bg[i] = Bb + (size_t)r * H + cs * 8;
        lb[i] = Bs + (wave * 4 + i) * 512;
    }

    f32x4 acc[2][4] = {};
    for (int k0 = 0; k0 < H; k0 += 64) {
#pragma unroll
        for (int i = 0; i < 2; ++i) gload16(ag[i] + k0, la[i]);
#pragma unroll
        for (int i = 0; i < 4; ++i) gload16(bg[i] + k0, lb[i]);
        __syncthreads();
#pragma unroll
        for (int kh = 0; kh < 2; ++kh) {
            s16x8 af[2], bfr[4];
#pragma unroll
            for (int mi = 0; mi < 2; ++mi) {
                int row = wr * 32 + mi * 16 + l16;
                int ch = (kh * 4 + quad) ^ (row & 7);
                af[mi] = *(const s16x8*)&As[(row * 8 + ch) * 8];
            }
#pragma unroll
            for (int ni = 0; ni < 4; ++ni) {
                int row = wc * 64 + ni * 16 + l16;
                int ch = (kh * 4 + quad) ^ (row & 7);
                bfr[ni] = *(const s16x8*)&Bs[(row * 8 + ch) * 8];
            }
#pragma unroll
            for (int mi = 0; mi < 2; ++mi)
#pragma unroll
                for (int ni = 0; ni < 4; ++ni)
                    acc[mi][ni] = __builtin_amdgcn_mfma_f32_16x16x32_bf16(
                        af[mi], bfr[ni], acc[mi][ni], 0, 0, 0);
        }
        __syncthreads();
    }
#pragma unroll
    for (int mi = 0; mi < 2; ++mi)
#pragma unroll
        for (int i = 0; i < 4; ++i) {
            float v = acc[mi][0][i];
            v = fmaxf(v, acc[mi][1][i]);
            v = fmaxf(v, acc[mi][2][i]);
            v = fmaxf(v, acc[mi][3][i]);
            for (int s = 1; s < 16; s <<= 1) v = fmaxf(v, __shfl_xor(v, s));
            if (l16 == 0) redA[(wr * 32 + mi * 16 + quad * 4 + i) * 2 + wc] = v;
        }
#pragma unroll
    for (int ni = 0; ni < 4; ++ni) {
        float v = acc[0][ni][0];
#pragma unroll
        for (int mi = 0; mi < 2; ++mi)
#pragma unroll
            for (int i = 0; i < 4; ++i) v = fmaxf(v, acc[mi][ni][i]);
        for (int s = 16; s < 64; s <<= 1) v = fmaxf(v, __shfl_xor(v, s));
        if (quad == 0) redB[(wc * 64 + ni * 16 + l16) * 2 + wr] = v;
    }
    __syncthreads();
    size_t base = (size_t)(b * KK + k);
    if (tid < 64) {
        float v = fmaxf(redA[tid * 2 + 0], redA[tid * 2 + 1]);
        maxq_part[(base * 2 + rt) * 128 + qt * 64 + tid] = v;
    }
    if (tid < 128) {
        float v = fmaxf(redB[tid * 2 + 0], redB[tid * 2 + 1]);
        maxr_part[(base * 2 + qt) * 256 + rt * 128 + tid] = v;
    }
}

// ---------------------------------------------------------------- K3: alphas + wq (grid B)
__global__ __launch_bounds__(256) void k3_alphas_wq(
    const float* __restrict__ maxq_part, const float* __restrict__ maxr_part,
    const float* __restrict__ r_mask, const float* __restrict__ q_mask,
    float* __restrict__ wbuf) {
    int b = blockIdx.x;
    int t = threadIdx.x;
    __shared__ float red[256];
    float wq = 0.f;
    for (int k = 0; k < KK; ++k) {
        size_t base = (size_t)(b * KK + k);
        float vq = -1e30f;
        if (t < 128)
            vq = fast_tanh(fmaxf(maxq_part[(base * 2 + 0) * 128 + t],
                                 maxq_part[(base * 2 + 1) * 128 + t]));
        red[t] = vq; __syncthreads();
        for (int s = 128; s > 0; s >>= 1) { if (t < s) red[t] = fmaxf(red[t], red[t + s]); __syncthreads(); }
        float mxq = red[0]; __syncthreads();
        float eq = (t < 128) ? fexp2((vq - mxq) * LOG2E) : 0.f;
        red[t] = eq; __syncthreads();
        for (int s = 128; s > 0; s >>= 1) { if (t < s) red[t] += red[t + s]; __syncthreads(); }
        float invq = 1.f / red[0]; __syncthreads();
        if (t < 128) wq += eq * invq;
        float vr = fast_tanh(fmaxf(maxr_part[(base * 2 + 0) * 256 + t],
                                   maxr_part[(base * 2 + 1) * 256 + t]));
        red[t] = vr; __syncthreads();
        for (int s = 128; s > 0; s >>= 1) { if (t < s) red[t] = fmaxf(red[t], red[t + s]); __syncthreads(); }
        float mxr = red[0]; __syncthreads();
        float er = fexp2((vr - mxr) * LOG2E);
        red[t] = er; __syncthreads();
        for (int s = 128; s > 0; s >>= 1) { if (t < s) red[t] += red[t + s]; __syncthreads(); }
        float invr = 1.f / red[0];
        wbuf[b * LL + LQ + k * LR + t] = r_mask[base * LR + t] * er * invr;
        __syncthreads();
    }
    if (t < 128) wbuf[b * LL + t] = q_mask[b * LQ + t] * wq * 0.125f;
}

// ---------------------------------------------------------------- K4: big GEMM + fused logits
// 128(m) x 256(n) tile, BK=64; grid 1088 = 544 m-tiles x 2 n-tiles, XCD-swizzled.
// 64 MFMA per barrier per wave; 2-way logit partials.
__global__ __launch_bounds__(256) void k4_gemm_logits(
    const unsigned short* __restrict__ Xb, const unsigned short* __restrict__ Wqrb,
    const float* __restrict__ sWs, const float* __restrict__ Wqr_b,
    const float* __restrict__ Wc_w, const float* __restrict__ Vr_w,
    const float* __restrict__ wbuf, const float* __restrict__ qr_cov,
    float* __restrict__ logits) {
    __shared__ __align__(16) unsigned short As[128 * 64];  // 16 KB
    __shared__ __align__(16) unsigned short Bs[256 * 64];  // 32 KB
    __shared__ float wrow[128], covrow[128];
    __shared__ float sWsl[256], biasl[256], wcl[256], vrl[256];
    int tid = threadIdx.x;
    int wave = tid >> 6, lane = tid & 63;
    int quad = lane >> 4, l16 = lane & 15;
    int wr = wave >> 1, wc = wave & 1;
    // XCD swizzle: 1088 blocks = 8 XCDs x 136; consecutive tle within an XCD
    int g = blockIdx.x;
    int tle = (g & 7) * 136 + (g >> 3);
    int mt = tle >> 1, nt = tle & 1;
    size_t m0 = (size_t)mt * 128;          // global row (never crosses batch: 17*128 = LL)
    int n0 = nt * 256;
    int b = mt / 17;

    if (tid < 128) {
        wrow[tid]   = wbuf[m0 + tid];
        covrow[tid] = qr_cov[m0 + tid];
    }
    sWsl[tid]  = sWs[b * H + n0 + tid];
    biasl[tid] = Wqr_b[n0 + tid];
    wcl[tid]   = Wc_w[n0 + tid];
    vrl[tid]   = Vr_w[n0 + tid];

    const unsigned short* ag[4]; unsigned short* la[4];
    const unsigned short* bg[8]; unsigned short* lb[8];
#pragma unroll
    for (int i = 0; i < 4; ++i) {
        int gg = (wave * 4 + i) * 64 + lane;            // 0..1023
        int r = gg >> 3, c = gg & 7, cs = c ^ (r & 7);
        ag[i] = Xb + (m0 + r) * H + cs * 8;
        la[i] = As + (wave * 4 + i) * 512;
    }
#pragma unroll
    for (int i = 0; i < 8; ++i) {
        int gg = (wave * 8 + i) * 64 + lane;            // 0..2047
        int r = gg >> 3, c = gg & 7, cs = c ^ (r & 7);
        bg[i] = Wqrb + (size_t)(n0 + r) * H + cs * 8;
        lb[i] = Bs + (wave * 8 + i) * 512;
    }

    f32x4 acc[4][8] = {};
    for (int k0 = 0; k0 < H; k0 += 64) {
#pragma unroll
        for (int i = 0; i < 4; ++i) gload16(ag[i] + k0, la[i]);
#pragma unroll
        for (int i = 0; i < 8; ++i) gload16(bg[i] + k0, lb[i]);
        __syncthreads();
#pragma unroll
        for (int kh = 0; kh < 2; ++kh) {
            s16x8 af[4], bfr[8];
#pragma unroll
            for (int mi = 0; mi < 4; ++mi) {
                int row = wr * 64 + mi * 16 + l16;
                int ch = (kh * 4 + quad) ^ (row & 7);
                af[mi] = *(const s16x8*)&As[(row * 8 + ch) * 8];
            }
#pragma unroll
            for (int ni = 0; ni < 8; ++ni) {
                int row = wc * 128 + ni * 16 + l16;
                int ch = (kh * 4 + quad) ^ (row & 7);
                bfr[ni] = *(const s16x8*)&Bs[(row * 8 + ch) * 8];
            }
#pragma unroll
            for (int mi = 0; mi < 4; ++mi)
#pragma unroll
                for (int ni = 0; ni < 8; ++ni)
                    acc[mi][ni] = __builtin_amdgcn_mfma_f32_16x16x32_bf16(
                        af[mi], bfr[ni], acc[mi][ni], 0, 0, 0);
        }
        __syncthreads();
    }
#pragma unroll
    for (int mi = 0; mi < 4; ++mi)
#pragma unroll
        for (int i = 0; i < 4; ++i) {
            int rl = wr * 64 + mi * 16 + quad * 4 + i;
            float wv = wrow[rl], cv = covrow[rl];
            float lsum = 0.f;
#pragma unroll
            for (int ni = 0; ni < 8; ++ni) {
                int ol = wc * 128 + ni * 16 + l16;
                float dec = sWsl[ol] + wv * acc[mi][ni][i] + biasl[ol] + cv * wcl[ol];
                lsum += vrl[ol] * fast_tanh(dec);
            }
            for (int s = 1; s < 16; s <<= 1) lsum += __shfl_xor(lsum, s);
            if (l16 == 0) atomicAdd(&logits[m0 + rl], lsum);
        }
}

// ---------------------------------------------------------------- K5a: softmax -> a, new_cov, coef
__global__ __launch_bounds__(256) void k5a_softmax(
    const float* __restrict__ logits, const float* __restrict__ q_mask,
    const float* __restrict__ r_mask, const float* __restrict__ qr_cov,
    const float* __restrict__ wbuf, float* __restrict__ out,
    float* __restrict__ coef) {
    int b = blockIdx.x, t = threadIdx.x;
    __shared__ float lg[LL];
    __shared__ float red[256];
    float mx = -1e30f;
    for (int l = t; l < LL; l += 256) {
        float v = logits[b * LL + l];
        lg[l] = v;
        mx = fmaxf(mx, v);
    }
    red[t] = mx; __syncthreads();
    for (int s = 128; s > 0; s >>= 1) { if (t < s) red[t] = fmaxf(red[t], red[t + s]); __syncthreads(); }
    mx = red[0]; __syncthreads();
    float sum = 0.f;
    for (int l = t; l < LL; l += 256) {
        float e = fexp2((lg[l] - mx) * LOG2E);
        float m = (l < LQ) ? q_mask[b * LQ + l] : r_mask[b * (KK * LR) + l - LQ];
        float em = e * m;
        lg[l] = em;
        sum += em;
    }
    red[t] = sum; __syncthreads();
    for (int s = 128; s > 0; s >>= 1) { if (t < s) red[t] += red[t + s]; __syncthreads(); }
    float inv = 1.f / red[0];
    __syncthreads();
    float* aout = out + B * H + (size_t)b * LL;
    float* cov  = out + B * H + (size_t)B * LL + (size_t)b * LL;
    for (int l = t; l < LL; l += 256) {
        float a = lg[l] * inv;
        aout[l] = a;
        cov[l] = qr_cov[b * LL + l] + a;
        coef[b * LL + l] = a * wbuf[b * LL + l];
    }
}

// ---------------------------------------------------------------- K5b: c_t = sum_l coef_l * X_l
__global__ __launch_bounds__(256) void k5b_ct(
    const unsigned short* __restrict__ Xb, const float* __restrict__ coef,
    float* __restrict__ out) {
    int b = blockIdx.x / 17, chunk = blockIdx.x % 17;
    int t = threadIdx.x;
    int l0 = chunk * 128;
    __shared__ float cl[128];
    __shared__ float red[4][512];
    if (t < 128) cl[t] = coef[b * LL + l0 + t];
    __syncthreads();
    int rr = t >> 6, lane = t & 63, cc = lane * 8;
    float a[8] = {};
    const unsigned short* xp = Xb + ((size_t)b * LL + l0) * H;
    for (int l = rr; l < 128; l += 4) {
        float c = cl[l];
        uint4 u4 = *(const uint4*)(xp + (size_t)l * H + cc);
        a[0] += c * __uint_as_float(u4.x << 16);
        a[1] += c * __uint_as_float(u4.x & 0xffff0000u);
        a[2] += c * __uint_as_float(u4.y << 16);
        a[3] += c * __uint_as_float(u4.y & 0xffff0000u);
        a[4] += c * __uint_as_float(u4.z << 16);
        a[5] += c * __uint_as_float(u4.z & 0xffff0000u);
        a[6] += c * __uint_as_float(u4.w << 16);
        a[7] += c * __uint_as_float(u4.w & 0xffff0000u);
    }
#pragma unroll
    for (int j = 0; j < 8; ++j) red[rr][cc + j] = a[j];
    __syncthreads();
    int col = t * 2;
    float s0 = red[0][col] + red[1][col] + red[2][col] + red[3][col];
    float s1 = red[0][col + 1] + red[1][col + 1] + red[2][col + 1] + red[3][col + 1];
    atomicAdd(&out[b * H + col], s0);
    atomicAdd(&out[b * H + col + 1], s1);
}

// ================================================================ launch
extern "C" void kernel_launch(void* const* d_in, const int* in_sizes, int n_in,
                              void* d_out, int out_size, void* d_ws, size_t ws_size,
                              hipStream_t stream) {
    (void)in_sizes; (void)n_in; (void)out_size; (void)ws_size;
    const float* h_q    = (const float*)d_in[0];
    const float* q_mask = (const float*)d_in[1];
    const float* h_r    = (const float*)d_in[2];
    const float* r_mask = (const float*)d_in[3];
    const float* s_t    = (const float*)d_in[4];
    const float* qr_cov = (const float*)d_in[5];
    const float* U_w    = (const float*)d_in[6];
    const float* Wc_w   = (const float*)d_in[7];
    const float* Ws_w   = (const float*)d_in[8];
    const float* Wqr_w  = (const float*)d_in[9];
    const float* Wqr_b  = (const float*)d_in[10];
    const float* Vr_w   = (const float*)d_in[11];
    float* out = (float*)d_out;

    char* p = (char*)d_ws;
    unsigned short* Xb   = (unsigned short*)p; p += (size_t)B * LL * H * 2;
    unsigned short* Uwb  = (unsigned short*)p; p += (size_t)H * H * 2;
    unsigned short* Wqrb = (unsigned short*)p; p += (size_t)H * H * 2;
    unsigned short* hqU  = (unsigned short*)p; p += (size_t)B * LQ * H * 2;
    float* sWs       = (float*)p; p += (size_t)B * H * 4;
    float* maxq_part = (float*)p; p += (size_t)B * KK * 2 * 128 * 4;
    float* maxr_part = (float*)p; p += (size_t)B * KK * 2 * 256 * 4;
    float* wbuf      = (float*)p; p += (size_t)B * LL * 4;
    float* logits    = (float*)p; p += (size_t)B * LL * 4;
    float* coef      = (float*)p; p += (size_t)B * LL * 4;

    k0_convert<<<K0GRID + 256, 256, 0, stream>>>(h_q, h_r, U_w, Wqr_w, Xb, Uwb, Wqrb,
                                                 logits, out, s_t, Ws_w, sWs);
    k1_gemm_hqU<<<dim3((B * LQ) / 64, H / 64), 256, 0, stream>>>(Xb, Uwb, hqU);
    k2_scores<<<B * KK * 4, 256, 0, stream>>>(hqU, Xb, maxq_part, maxr_part);
    k3_alphas_wq<<<B, 256, 0, stream>>>(maxq_part, maxr_part, r_mask, q_mask, wbuf);
    k4_gemm_logits<<<1088, 256, 0, stream>>>(
        Xb, Wqrb, sWs, Wqr_b, Wc_w, Vr_w, wbuf, qr_cov, logits);
    k5a_softmax<<<B, 256, 0, stream>>>(logits, q_mask, r_mask, qr_cov, wbuf, out, coef);
    k5b_ct<<<B * (LL / 128), 256, 0, stream>>>(Xb, coef, out);
}

// Round 5
// 363.372 us; speedup vs baseline: 1.1943x; 1.1943x over previous
//
#include <hip/hip_runtime.h>
#include <stdint.h>

#define B  32
#define KK 8
#define LQ 128
#define LR 256
#define H  512
#define LL 2176   // LQ + KK*LR

typedef short s16x8 __attribute__((ext_vector_type(8)));
typedef float f32x4 __attribute__((ext_vector_type(4)));

__device__ __forceinline__ unsigned short f2bf(float f) {
    unsigned int u = __float_as_uint(f);
    unsigned int r = (u + 0x7FFFu + ((u >> 16) & 1u)) >> 16;
    return (unsigned short)r;
}
__device__ __forceinline__ void gload16(const unsigned short* g, unsigned short* l) {
    __builtin_amdgcn_global_load_lds(
        (const __attribute__((address_space(1))) void*)g,
        (__attribute__((address_space(3))) void*)l, 16, 0, 0);
}
__device__ __forceinline__ float fexp2(float x) {
#if __has_builtin(__builtin_amdgcn_exp2f)
    return __builtin_amdgcn_exp2f(x);
#else
    return __expf(x * 0.69314718056f);
#endif
}
__device__ __forceinline__ float frcp(float x) {
#if __has_builtin(__builtin_amdgcn_rcpf)
    return __builtin_amdgcn_rcpf(x);
#else
    return 1.f / x;
#endif
}
__device__ __forceinline__ float fast_tanh(float x) {
    float e = fexp2(x * 2.885390082f);
    return 1.f - 2.f * frcp(1.f + e);
}
#define LOG2E 1.4426950408889634f

// ---------------------------------------------------------------- K0: fp32->bf16 + zero + sWs
#define NQ4 (B * LQ * H / 4)        // 524288
#define NR4 (B * KK * LR * H / 4)   // 8388608
#define NW4 (H * H / 4)             // 65536
#define NL4 (B * LL / 4)            // 17408  (logits)
#define NC4 (B * H / 4)             // 4096   (c_t)
#define NWB4 (B * LL / 4)           // 17408  (wbuf)
#define NZ4 (NL4 + NC4 + NWB4)
#define NTOT4 (NQ4 + NR4 + 2 * NW4 + NZ4)
#define K0GRID 2048
__global__ __launch_bounds__(256) void k0_convert(
    const float* __restrict__ h_q, const float* __restrict__ h_r,
    const float* __restrict__ U_w, const float* __restrict__ Wqr_w,
    unsigned short* __restrict__ Xb, unsigned short* __restrict__ Uwb,
    unsigned short* __restrict__ Wqrb, float* __restrict__ logits,
    float* __restrict__ out_ct, float* __restrict__ wbuf,
    const float* __restrict__ s_t, const float* __restrict__ Ws_w,
    float* __restrict__ sWs) {
    int t = threadIdx.x;
    if (blockIdx.x >= K0GRID) {
        // sWs: 256 blocks, (b, oc)
        int idx = blockIdx.x - K0GRID;
        int b = idx >> 3, oc = idx & 7;
        __shared__ __align__(16) float sl[H];
        for (int i = t; i < H; i += 256) sl[i] = s_t[b * H + i];
        __syncthreads();
        int o = oc * 64 + (t >> 2);
        int part = t & 3;
        const float4* sl4 = (const float4*)sl;
        const float4* wr4 = (const float4*)(Ws_w + (size_t)o * H);
        float a = 0.f;
        for (int i = part * 32; i < part * 32 + 32; ++i) {
            float4 x = sl4[i], y = wr4[i];
            a += x.x * y.x + x.y * y.y + x.z * y.z + x.w * y.w;
        }
        a += __shfl_xor(a, 1);
        a += __shfl_xor(a, 2);
        if (part == 0) sWs[b * H + o] = a;
        return;
    }
    for (unsigned int u = blockIdx.x * 256 + t; u < NTOT4; u += K0GRID * 256) {
        if (u < NQ4 + NR4) {
            const float* src; unsigned short* dst;
            if (u < NQ4) {
                unsigned int f = u * 4;
                unsigned int b = f >> 16, rem = f & 65535u;  // LQ*H = 65536
                src = h_q + f;
                dst = Xb + (size_t)b * (LL * H) + rem;
            } else {
                unsigned int f = (u - NQ4) * 4;
                unsigned int b = f >> 20, rem = f & 1048575u; // KK*LR*H = 1048576
                src = h_r + f;
                dst = Xb + (size_t)b * (LL * H) + LQ * H + rem;
            }
            float4 v = *(const float4*)src;
            ushort4 o;
            o.x = f2bf(v.x); o.y = f2bf(v.y); o.z = f2bf(v.z); o.w = f2bf(v.w);
            *(ushort4*)dst = o;
        } else if (u < NQ4 + NR4 + 2 * NW4) {
            unsigned int v4 = u - (NQ4 + NR4);
            const float* src = (v4 < NW4) ? (U_w + v4 * 4) : (Wqr_w + (v4 - NW4) * 4);
            unsigned short* dst = (v4 < NW4) ? (Uwb + v4 * 4) : (Wqrb + (v4 - NW4) * 4);
            float4 v = *(const float4*)src;
            ushort4 o;
            o.x = f2bf(v.x); o.y = f2bf(v.y); o.z = f2bf(v.z); o.w = f2bf(v.w);
            *(ushort4*)dst = o;
        } else {
            unsigned int z = u - (NQ4 + NR4 + 2 * NW4);
            float4 zero = {0.f, 0.f, 0.f, 0.f};
            if (z < NL4) *(float4*)(logits + z * 4) = zero;
            else if (z < NL4 + NC4) *(float4*)(out_ct + (z - NL4) * 4) = zero;
            else *(float4*)(wbuf + (z - NL4 - NC4) * 4) = zero;
        }
    }
}

// ---------------------------------------------------------------- K1: hqU = Xq @ Uw^T (bf16)
// 64(m) x 128(n) tiles, BK=64, glds staging. grid 256 = 64 mt x 4 nt, XCD-swizzled.
__global__ __launch_bounds__(256) void k1_gemm_hqU(
    const unsigned short* __restrict__ Xb, const unsigned short* __restrict__ Uwb,
    unsigned short* __restrict__ hqU) {
    __shared__ __align__(16) unsigned short As[64 * 64];   //  8 KB
    __shared__ __align__(16) unsigned short Bs[128 * 64];  // 16 KB
    int tid = threadIdx.x;
    int wave = tid >> 6, lane = tid & 63;
    int quad = lane >> 4, l16 = lane & 15;
    int wr = wave >> 1, wc = wave & 1;
    int g = blockIdx.x;
    int tle = (g & 7) * 32 + (g >> 3);
    int mt = tle >> 2, nt = tle & 3;
    int m0 = mt * 64, n0 = nt * 128;

    const unsigned short* ag[2]; unsigned short* la[2];
    const unsigned short* bg[4]; unsigned short* lb[4];
#pragma unroll
    for (int i = 0; i < 2; ++i) {
        int gg = (wave * 2 + i) * 64 + lane;
        int r = gg >> 3, c = gg & 7, cs = c ^ (r & 7);
        int am = m0 + r;
        ag[i] = Xb + ((size_t)(am >> 7) * LL + (am & 127)) * H + cs * 8;
        la[i] = As + (wave * 2 + i) * 512;
    }
#pragma unroll
    for (int i = 0; i < 4; ++i) {
        int gg = (wave * 4 + i) * 64 + lane;
        int r = gg >> 3, c = gg & 7, cs = c ^ (r & 7);
        bg[i] = Uwb + (size_t)(n0 + r) * H + cs * 8;
        lb[i] = Bs + (wave * 4 + i) * 512;
    }

    f32x4 acc[2][4] = {};
    for (int k0 = 0; k0 < H; k0 += 64) {
#pragma unroll
        for (int i = 0; i < 2; ++i) gload16(ag[i] + k0, la[i]);
#pragma unroll
        for (int i = 0; i < 4; ++i) gload16(bg[i] + k0, lb[i]);
        __syncthreads();
#pragma unroll
        for (int kh = 0; kh < 2; ++kh) {
            s16x8 af[2], bfr[4];
#pragma unroll
            for (int mi = 0; mi < 2; ++mi) {
                int row = wr * 32 + mi * 16 + l16;
                int ch = (kh * 4 + quad) ^ (row & 7);
                af[mi] = *(const s16x8*)&As[(row * 8 + ch) * 8];
            }
#pragma unroll
            for (int ni = 0; ni < 4; ++ni) {
                int row = wc * 64 + ni * 16 + l16;
                int ch = (kh * 4 + quad) ^ (row & 7);
                bfr[ni] = *(const s16x8*)&Bs[(row * 8 + ch) * 8];
            }
#pragma unroll
            for (int mi = 0; mi < 2; ++mi)
#pragma unroll
                for (int ni = 0; ni < 4; ++ni)
                    acc[mi][ni] = __builtin_amdgcn_mfma_f32_16x16x32_bf16(
                        af[mi], bfr[ni], acc[mi][ni], 0, 0, 0);
        }
        __syncthreads();
    }
#pragma unroll
    for (int mi = 0; mi < 2; ++mi)
#pragma unroll
        for (int ni = 0; ni < 4; ++ni)
#pragma unroll
            for (int i = 0; i < 4; ++i) {
                int row = m0 + wr * 32 + mi * 16 + quad * 4 + i;
                int col = n0 + wc * 64 + ni * 16 + l16;
                hqU[(size_t)row * H + col] = f2bf(acc[mi][ni][i]);
            }
}

// ---------------------------------------------------------------- K2: score maxes
// 64(q) x 256(r) tiles, BK=64. grid 512 = (b,k,qt), XCD-swizzled. maxq complete,
// maxr partial over qt.
__global__ __launch_bounds__(256) void k2_scores(
    const unsigned short* __restrict__ hqU, const unsigned short* __restrict__ Xb,
    float* __restrict__ maxq, float* __restrict__ maxr_part) {
    __shared__ __align__(16) unsigned short As[64 * 64];   //  8 KB
    __shared__ __align__(16) unsigned short Bs[256 * 64];  // 32 KB
    __shared__ float redA[64 * 2];
    __shared__ float redB[256 * 2];
    int g = blockIdx.x;
    int tle = (g & 7) * 64 + (g >> 3);
    int qt = tle & 1, k = (tle >> 1) & 7, b = tle >> 4;
    int tid = threadIdx.x;
    int wave = tid >> 6, lane = tid & 63;
    int quad = lane >> 4, l16 = lane & 15;
    int wr = wave >> 1, wc = wave & 1;

    const unsigned short* Ab = hqU + (size_t)(b * LQ + qt * 64) * H;
    const unsigned short* Bb = Xb + (size_t)(b * LL + LQ + k * LR) * H;

    const unsigned short* ag[2]; unsigned short* la[2];
    const unsigned short* bg[8]; unsigned short* lb[8];
#pragma unroll
    for (int i = 0; i < 2; ++i) {
        int gg = (wave * 2 + i) * 64 + lane;
        int r = gg >> 3, c = gg & 7, cs = c ^ (r & 7);
        ag[i] = Ab + (size_t)r * H + cs * 8;
        la[i] = As + (wave * 2 + i) * 512;
    }
#pragma unroll
    for (int i = 0; i < 8; ++i) {
        int gg = (wave * 8 + i) * 64 + lane;
        int r = gg >> 3, c = gg & 7, cs = c ^ (r & 7);
        bg[i] = Bb + (size_t)r * H + cs * 8;
        lb[i] = Bs + (wave * 8 + i) * 512;
    }

    f32x4 acc[2][8] = {};
    for (int k0 = 0; k0 < H; k0 += 64) {
#pragma unroll
        for (int i = 0; i < 2; ++i) gload16(ag[i] + k0, la[i]);
#pragma unroll
        for (int i = 0; i < 8; ++i) gload16(bg[i] + k0, lb[i]);
        __syncthreads();
#pragma unroll
        for (int kh = 0; kh < 2; ++kh) {
            s16x8 af[2], bfr[8];
#pragma unroll
            for (int mi = 0; mi < 2; ++mi) {
                int row = wr * 32 + mi * 16 + l16;
                int ch = (kh * 4 + quad) ^ (row & 7);
                af[mi] = *(const s16x8*)&As[(row * 8 + ch) * 8];
            }
#pragma unroll
            for (int ni = 0; ni < 8; ++ni) {
                int row = wc * 128 + ni * 16 + l16;
                int ch = (kh * 4 + quad) ^ (row & 7);
                bfr[ni] = *(const s16x8*)&Bs[(row * 8 + ch) * 8];
            }
#pragma unroll
            for (int mi = 0; mi < 2; ++mi)
#pragma unroll
                for (int ni = 0; ni < 8; ++ni)
                    acc[mi][ni] = __builtin_amdgcn_mfma_f32_16x16x32_bf16(
                        af[mi], bfr[ni], acc[mi][ni], 0, 0, 0);
        }
        __syncthreads();
    }
    // row maxes over this block's 128 r-cols (wc half), combine halves via LDS
#pragma unroll
    for (int mi = 0; mi < 2; ++mi)
#pragma unroll
        for (int i = 0; i < 4; ++i) {
            float v = acc[mi][0][i];
#pragma unroll
            for (int ni = 1; ni < 8; ++ni) v = fmaxf(v, acc[mi][ni][i]);
            for (int s = 1; s < 16; s <<= 1) v = fmaxf(v, __shfl_xor(v, s));
            if (l16 == 0) redA[(wr * 32 + mi * 16 + quad * 4 + i) * 2 + wc] = v;
        }
    // col maxes over this block's 64 q-rows
#pragma unroll
    for (int ni = 0; ni < 8; ++ni) {
        float v = acc[0][ni][0];
#pragma unroll
        for (int mi = 0; mi < 2; ++mi)
#pragma unroll
            for (int i = 0; i < 4; ++i) v = fmaxf(v, acc[mi][ni][i]);
        for (int s = 16; s < 64; s <<= 1) v = fmaxf(v, __shfl_xor(v, s));
        if (quad == 0) redB[(wc * 128 + ni * 16 + l16) * 2 + wr] = v;
    }
    __syncthreads();
    size_t bk = (size_t)(b * KK + k);
    if (tid < 64)
        maxq[bk * 128 + qt * 64 + tid] = fmaxf(redA[tid * 2 + 0], redA[tid * 2 + 1]);
    maxr_part[(bk * 2 + qt) * 256 + tid] = fmaxf(redB[tid * 2 + 0], redB[tid * 2 + 1]);
}

// ---------------------------------------------------------------- K3: alphas + wq (grid B*KK)
__global__ __launch_bounds__(256) void k3_alphas(
    const float* __restrict__ maxq, const float* __restrict__ maxr_part,
    const float* __restrict__ r_mask, const float* __restrict__ q_mask,
    float* __restrict__ wbuf) {
    int b = blockIdx.x >> 3, k = blockIdx.x & 7;
    int t = threadIdx.x;
    __shared__ float red[256];
    size_t bk = (size_t)(b * KK + k);
    // alpha_q over LQ=128 (maxq already complete)
    float vq = -1e30f;
    if (t < 128) vq = fast_tanh(maxq[bk * 128 + t]);
    red[t] = vq; __syncthreads();
    for (int s = 128; s > 0; s >>= 1) { if (t < s) red[t] = fmaxf(red[t], red[t + s]); __syncthreads(); }
    float mxq = red[0]; __syncthreads();
    float eq = (t < 128) ? fexp2((vq - mxq) * LOG2E) : 0.f;
    red[t] = eq; __syncthreads();
    for (int s = 128; s > 0; s >>= 1) { if (t < s) red[t] += red[t + s]; __syncthreads(); }
    float invq = 1.f / red[0]; __syncthreads();
    if (t < 128)
        atomicAdd(&wbuf[b * LL + t], q_mask[b * LQ + t] * eq * invq * 0.125f);
    // alpha_r over LR=256
    float vr = fast_tanh(fmaxf(maxr_part[(bk * 2 + 0) * 256 + t],
                               maxr_part[(bk * 2 + 1) * 256 + t]));
    red[t] = vr; __syncthreads();
    for (int s = 128; s > 0; s >>= 1) { if (t < s) red[t] = fmaxf(red[t], red[t + s]); __syncthreads(); }
    float mxr = red[0]; __syncthreads();
    float er = fexp2((vr - mxr) * LOG2E);
    red[t] = er; __syncthreads();
    for (int s = 128; s > 0; s >>= 1) { if (t < s) red[t] += red[t + s]; __syncthreads(); }
    float invr = 1.f / red[0];
    wbuf[b * LL + LQ + k * LR + t] = r_mask[bk * LR + t] * er * invr;
}

// ---------------------------------------------------------------- K4: big GEMM + fused logits
// 128x128 tile, BK=64; grid 2176 = 544 mt x 4 nt, XCD-swizzled (4 nt consecutive).
__global__ __launch_bounds__(256) void k4_gemm_logits(
    const unsigned short* __restrict__ Xb, const unsigned short* __restrict__ Wqrb,
    const float* __restrict__ sWs, const float* __restrict__ Wqr_b,
    const float* __restrict__ Wc_w, const float* __restrict__ Vr_w,
    const float* __restrict__ wbuf, const float* __restrict__ qr_cov,
    float* __restrict__ logits) {
    __shared__ __align__(16) unsigned short As[128 * 64];  // 16 KB
    __shared__ __align__(16) unsigned short Bs[128 * 64];  // 16 KB
    __shared__ float wrow[128], covrow[128], sWsl[128], biasl[128], wcl[128], vrl[128];
    int tid = threadIdx.x;
    int wave = tid >> 6, lane = tid & 63;
    int quad = lane >> 4, l16 = lane & 15;
    int wr = wave >> 1, wc = wave & 1;
    int g = blockIdx.x;
    int tle = (g & 7) * 272 + (g >> 3);
    int mt = tle >> 2, nt = tle & 3;
    size_t m0 = (size_t)mt * 128;     // never crosses batch: LL = 17*128
    int n0 = nt * 128;
    int b = mt / 17;

    if (tid < 128) {
        wrow[tid]   = wbuf[m0 + tid];
        covrow[tid] = qr_cov[m0 + tid];
        sWsl[tid]   = sWs[b * H + n0 + tid];
        biasl[tid]  = Wqr_b[n0 + tid];
        wcl[tid]    = Wc_w[n0 + tid];
        vrl[tid]    = Vr_w[n0 + tid];
    }

    const unsigned short* ag[4]; unsigned short* la[4];
    const unsigned short* bg[4]; unsigned short* lb[4];
#pragma unroll
    for (int i = 0; i < 4; ++i) {
        int gg = (wave * 4 + i) * 64 + lane;
        int r = gg >> 3, c = gg & 7, cs = c ^ (r & 7);
        ag[i] = Xb + (m0 + r) * H + cs * 8;
        bg[i] = Wqrb + (size_t)(n0 + r) * H + cs * 8;
        la[i] = As + (wave * 4 + i) * 512;
        lb[i] = Bs + (wave * 4 + i) * 512;
    }

    f32x4 acc[4][4] = {};
    for (int k0 = 0; k0 < H; k0 += 64) {
#pragma unroll
        for (int i = 0; i < 4; ++i) gload16(ag[i] + k0, la[i]);
#pragma unroll
        for (int i = 0; i < 4; ++i) gload16(bg[i] + k0, lb[i]);
        __syncthreads();
#pragma unroll
        for (int kh = 0; kh < 2; ++kh) {
            s16x8 af[4], bfr[4];
#pragma unroll
            for (int mi = 0; mi < 4; ++mi) {
                int row = wr * 64 + mi * 16 + l16;
                int ch = (kh * 4 + quad) ^ (row & 7);
                af[mi] = *(const s16x8*)&As[(row * 8 + ch) * 8];
            }
#pragma unroll
            for (int ni = 0; ni < 4; ++ni) {
                int row = wc * 64 + ni * 16 + l16;
                int ch = (kh * 4 + quad) ^ (row & 7);
                bfr[ni] = *(const s16x8*)&Bs[(row * 8 + ch) * 8];
            }
#pragma unroll
            for (int mi = 0; mi < 4; ++mi)
#pragma unroll
                for (int ni = 0; ni < 4; ++ni)
                    acc[mi][ni] = __builtin_amdgcn_mfma_f32_16x16x32_bf16(
                        af[mi], bfr[ni], acc[mi][ni], 0, 0, 0);
        }
        __syncthreads();
    }
#pragma unroll
    for (int mi = 0; mi < 4; ++mi)
#pragma unroll
        for (int i = 0; i < 4; ++i) {
            int rl = wr * 64 + mi * 16 + quad * 4 + i;
            float wv = wrow[rl], cv = covrow[rl];
            float lsum = 0.f;
#pragma unroll
            for (int ni = 0; ni < 4; ++ni) {
                int ol = wc * 64 + ni * 16 + l16;
                float dec = sWsl[ol] + wv * acc[mi][ni][i] + biasl[ol] + cv * wcl[ol];
                lsum += vrl[ol] * fast_tanh(dec);
            }
            for (int s = 1; s < 16; s <<= 1) lsum += __shfl_xor(lsum, s);
            if (l16 == 0) atomicAdd(&logits[m0 + rl], lsum);
        }
}

// ---------------------------------------------------------------- K5a: softmax -> a, new_cov, coef
__global__ __launch_bounds__(256) void k5a_softmax(
    const float* __restrict__ logits, const float* __restrict__ q_mask,
    const float* __restrict__ r_mask, const float* __restrict__ qr_cov,
    const float* __restrict__ wbuf, float* __restrict__ out,
    float* __restrict__ coef) {
    int b = blockIdx.x, t = threadIdx.x;
    __shared__ float lg[LL];
    __shared__ float red[256];
    float mx = -1e30f;
    for (int l = t; l < LL; l += 256) {
        float v = logits[b * LL + l];
        lg[l] = v;
        mx = fmaxf(mx, v);
    }
    red[t] = mx; __syncthreads();
    for (int s = 128; s > 0; s >>= 1) { if (t < s) red[t] = fmaxf(red[t], red[t + s]); __syncthreads(); }
    mx = red[0]; __syncthreads();
    float sum = 0.f;
    for (int l = t; l < LL; l += 256) {
        float e = fexp2((lg[l] - mx) * LOG2E);
        float m = (l < LQ) ? q_mask[b * LQ + l] : r_mask[b * (KK * LR) + l - LQ];
        float em = e * m;
        lg[l] = em;
        sum += em;
    }
    red[t] = sum; __syncthreads();
    for (int s = 128; s > 0; s >>= 1) { if (t < s) red[t] += red[t + s]; __syncthreads(); }
    float inv = 1.f / red[0];
    __syncthreads();
    float* aout = out + B * H + (size_t)b * LL;
    float* cov  = out + B * H + (size_t)B * LL + (size_t)b * LL;
    for (int l = t; l < LL; l += 256) {
        float a = lg[l] * inv;
        aout[l] = a;
        cov[l] = qr_cov[b * LL + l] + a;
        coef[b * LL + l] = a * wbuf[b * LL + l];
    }
}

// ---------------------------------------------------------------- K5b: c_t = sum_l coef_l * X_l
__global__ __launch_bounds__(256) void k5b_ct(
    const unsigned short* __restrict__ Xb, const float* __restrict__ coef,
    float* __restrict__ out) {
    int b = blockIdx.x / 17, chunk = blockIdx.x % 17;
    int t = threadIdx.x;
    int l0 = chunk * 128;
    __shared__ float cl[128];
    __shared__ float red[4][512];
    if (t < 128) cl[t] = coef[b * LL + l0 + t];
    __syncthreads();
    int rr = t >> 6, lane = t & 63, cc = lane * 8;
    float a[8] = {};
    const unsigned short* xp = Xb + ((size_t)b * LL + l0) * H;
    for (int l = rr; l < 128; l += 4) {
        float c = cl[l];
        uint4 u4 = *(const uint4*)(xp + (size_t)l * H + cc);
        a[0] += c * __uint_as_float(u4.x << 16);
        a[1] += c * __uint_as_float(u4.x & 0xffff0000u);
        a[2] += c * __uint_as_float(u4.y << 16);
        a[3] += c * __uint_as_float(u4.y & 0xffff0000u);
        a[4] += c * __uint_as_float(u4.z << 16);
        a[5] += c * __uint_as_float(u4.z & 0xffff0000u);
        a[6] += c * __uint_as_float(u4.w << 16);
        a[7] += c * __uint_as_float(u4.w & 0xffff0000u);
    }
#pragma unroll
    for (int j = 0; j < 8; ++j) red[rr][cc + j] = a[j];
    __syncthreads();
    int col = t * 2;
    float s0 = red[0][col] + red[1][col] + red[2][col] + red[3][col];
    float s1 = red[0][col + 1] + red[1][col + 1] + red[2][col + 1] + red[3][col + 1];
    atomicAdd(&out[b * H + col], s0);
    atomicAdd(&out[b * H + col + 1], s1);
}

// ================================================================ launch
extern "C" void kernel_launch(void* const* d_in, const int* in_sizes, int n_in,
                              void* d_out, int out_size, void* d_ws, size_t ws_size,
                              hipStream_t stream) {
    (void)in_sizes; (void)n_in; (void)out_size; (void)ws_size;
    const float* h_q    = (const float*)d_in[0];
    const float* q_mask = (const float*)d_in[1];
    const float* h_r    = (const float*)d_in[2];
    const float* r_mask = (const float*)d_in[3];
    const float* s_t    = (const float*)d_in[4];
    const float* qr_cov = (const float*)d_in[5];
    const float* U_w    = (const float*)d_in[6];
    const float* Wc_w   = (const float*)d_in[7];
    const float* Ws_w   = (const float*)d_in[8];
    const float* Wqr_w  = (const float*)d_in[9];
    const float* Wqr_b  = (const float*)d_in[10];
    const float* Vr_w   = (const float*)d_in[11];
    float* out = (float*)d_out;

    char* p = (char*)d_ws;
    unsigned short* Xb   = (unsigned short*)p; p += (size_t)B * LL * H * 2;
    unsigned short* Uwb  = (unsigned short*)p; p += (size_t)H * H * 2;
    unsigned short* Wqrb = (unsigned short*)p; p += (size_t)H * H * 2;
    unsigned short* hqU  = (unsigned short*)p; p += (size_t)B * LQ * H * 2;
    float* sWs       = (float*)p; p += (size_t)B * H * 4;
    float* maxq      = (float*)p; p += (size_t)B * KK * 128 * 4;
    float* maxr_part = (float*)p; p += (size_t)B * KK * 2 * 256 * 4;
    float* wbuf      = (float*)p; p += (size_t)B * LL * 4;
    float* logits    = (float*)p; p += (size_t)B * LL * 4;
    float* coef      = (float*)p; p += (size_t)B * LL * 4;

    k0_convert<<<K0GRID + 256, 256, 0, stream>>>(h_q, h_r, U_w, Wqr_w, Xb, Uwb, Wqrb,
                                                 logits, out, wbuf, s_t, Ws_w, sWs);
    k1_gemm_hqU<<<256, 256, 0, stream>>>(Xb, Uwb, hqU);
    k2_scores<<<512, 256, 0, stream>>>(hqU, Xb, maxq, maxr_part);
    k3_alphas<<<B * KK, 256, 0, stream>>>(maxq, maxr_part, r_mask, q_mask, wbuf);
    k4_gemm_logits<<<2176, 256, 0, stream>>>(
        Xb, Wqrb, sWs, Wqr_b, Wc_w, Vr_w, wbuf, qr_cov, logits);
    k5a_softmax<<<B, 256, 0, stream>>>(logits, q_mask, r_mask, qr_cov, wbuf, out, coef);
    k5b_ct<<<B * (LL / 128), 256, 0, stream>>>(Xb, coef, out);
}

// Round 6
// 345.332 us; speedup vs baseline: 1.2567x; 1.0522x over previous
//
#include <hip/hip_runtime.h>
#include <stdint.h>

#define B  32
#define KK 8
#define LQ 128
#define LR 256
#define H  512
#define LL 2176   // LQ + KK*LR

typedef short s16x8 __attribute__((ext_vector_type(8)));
typedef float f32x4 __attribute__((ext_vector_type(4)));

__device__ __forceinline__ unsigned short f2bf(float f) {
    unsigned int u = __float_as_uint(f);
    unsigned int r = (u + 0x7FFFu + ((u >> 16) & 1u)) >> 16;
    return (unsigned short)r;
}
__device__ __forceinline__ void gload16(const unsigned short* g, unsigned short* l) {
    __builtin_amdgcn_global_load_lds(
        (const __attribute__((address_space(1))) void*)g,
        (__attribute__((address_space(3))) void*)l, 16, 0, 0);
}
__device__ __forceinline__ float fexp2(float x) {
#if __has_builtin(__builtin_amdgcn_exp2f)
    return __builtin_amdgcn_exp2f(x);
#else
    return __expf(x * 0.69314718056f);
#endif
}
__device__ __forceinline__ float frcp(float x) {
#if __has_builtin(__builtin_amdgcn_rcpf)
    return __builtin_amdgcn_rcpf(x);
#else
    return 1.f / x;
#endif
}
__device__ __forceinline__ float fast_tanh(float x) {
    float e = fexp2(x * 2.885390082f);
    return 1.f - 2.f * frcp(1.f + e);
}
#define LOG2E 1.4426950408889634f

// ---------------------------------------------------------------- K0: fp32->bf16 + zero + sWs
// Block-region specialization; each convert/zero block handles 2048 float4
// (8 per thread, independent loads for MLP). All regions are 2048-f4 aligned.
#define NQ4 (B * LQ * H / 4)        // 524288
#define NR4 (B * KK * LR * H / 4)   // 8388608
#define NW4 (H * H / 4)             // 65536
#define NL4 (B * LL / 4)            // 17408  (logits)
#define NC4 (B * H / 4)             // 4096   (c_t)
#define NWB4 (B * LL / 4)           // 17408  (wbuf)
#define QBLK 256                    // NQ4 / 2048
#define RBLK 4096                   // NR4 / 2048
#define WBLK 64                     // 2*NW4 / 2048
#define ZBLK 19                     // (NL4+NC4+NWB4) / 2048 = 38912/2048
#define SBLK 256
#define K0GRID (QBLK + RBLK + WBLK + ZBLK + SBLK)  // 4691
__global__ __launch_bounds__(256) void k0_convert(
    const float* __restrict__ h_q, const float* __restrict__ h_r,
    const float* __restrict__ U_w, const float* __restrict__ Wqr_w,
    unsigned short* __restrict__ Xb, unsigned short* __restrict__ Uwb,
    unsigned short* __restrict__ Wqrb, float* __restrict__ logits,
    float* __restrict__ out_ct, float* __restrict__ wbuf,
    const float* __restrict__ s_t, const float* __restrict__ Ws_w,
    float* __restrict__ sWs) {
    int t = threadIdx.x;
    int blk = blockIdx.x;
    ushort4* Xb4 = (ushort4*)Xb;
    if (blk < QBLK + RBLK) {
        const float4* src; ushort4* dst;
        if (blk < QBLK) {
            unsigned u0 = (unsigned)blk * 2048u;
            unsigned b = (unsigned)blk >> 3;          // 8 blocks per batch
            src = (const float4*)h_q + u0;
            dst = Xb4 + b * 278528u + (u0 & 16383u);  // LL*H/4 = 278528, LQ*H/4 = 16384
        } else {
            unsigned rb = (unsigned)(blk - QBLK);
            unsigned u0 = rb * 2048u;
            unsigned b = rb >> 7;                     // 128 blocks per batch
            src = (const float4*)h_r + u0;
            dst = Xb4 + b * 278528u + 16384u + (u0 & 262143u);
        }
        float4 v[8];
#pragma unroll
        for (int j = 0; j < 8; ++j) v[j] = src[t + j * 256];
#pragma unroll
        for (int j = 0; j < 8; ++j) {
            ushort4 o;
            o.x = f2bf(v[j].x); o.y = f2bf(v[j].y);
            o.z = f2bf(v[j].z); o.w = f2bf(v[j].w);
            dst[t + j * 256] = o;
        }
    } else if (blk < QBLK + RBLK + WBLK) {
        int wb = blk - (QBLK + RBLK);
        const float4* src = ((wb < 32) ? (const float4*)U_w : (const float4*)Wqr_w)
                            + (unsigned)(wb & 31) * 2048u;
        ushort4* dst = ((wb < 32) ? (ushort4*)Uwb : (ushort4*)Wqrb)
                       + (unsigned)(wb & 31) * 2048u;
        float4 v[8];
#pragma unroll
        for (int j = 0; j < 8; ++j) v[j] = src[t + j * 256];
#pragma unroll
        for (int j = 0; j < 8; ++j) {
            ushort4 o;
            o.x = f2bf(v[j].x); o.y = f2bf(v[j].y);
            o.z = f2bf(v[j].z); o.w = f2bf(v[j].w);
            dst[t + j * 256] = o;
        }
    } else if (blk < QBLK + RBLK + WBLK + ZBLK) {
        unsigned zb = (unsigned)(blk - (QBLK + RBLK + WBLK));
        float4 zero = {0.f, 0.f, 0.f, 0.f};
        float4* lg4 = (float4*)logits;
        float4* ct4 = (float4*)out_ct;
        float4* wb4 = (float4*)wbuf;
#pragma unroll
        for (int j = 0; j < 8; ++j) {
            unsigned z = zb * 2048u + (unsigned)j * 256u + (unsigned)t;
            if (z < NL4) lg4[z] = zero;
            else if (z < NL4 + NC4) ct4[z - NL4] = zero;
            else if (z < NL4 + NC4 + NWB4) wb4[z - NL4 - NC4] = zero;
        }
    } else {
        // sWs: 256 blocks, (b, oc); bank-conflict-free interleave i = part + 4*ii
        int idx = blk - (QBLK + RBLK + WBLK + ZBLK);
        int b = idx >> 3, oc = idx & 7;
        __shared__ __align__(16) float sl[H];
        for (int i = t; i < H; i += 256) sl[i] = s_t[b * H + i];
        __syncthreads();
        int o = oc * 64 + (t >> 2);
        int part = t & 3;
        const float4* sl4 = (const float4*)sl;
        const float4* wr4 = (const float4*)(Ws_w + (size_t)o * H);
        float a = 0.f;
#pragma unroll
        for (int ii = 0; ii < 32; ++ii) {
            int i = part + 4 * ii;
            float4 x = sl4[i], y = wr4[i];
            a += x.x * y.x + x.y * y.y + x.z * y.z + x.w * y.w;
        }
        a += __shfl_xor(a, 1);
        a += __shfl_xor(a, 2);
        if (part == 0) sWs[b * H + o] = a;
    }
}

// ---------------------------------------------------------------- K1: hqU = Xq @ Uw^T (bf16)
// 64(m) x 128(n) tiles, BK=64, glds staging. grid 256 = 64 mt x 4 nt, XCD-swizzled.
__global__ __launch_bounds__(256) void k1_gemm_hqU(
    const unsigned short* __restrict__ Xb, const unsigned short* __restrict__ Uwb,
    unsigned short* __restrict__ hqU) {
    __shared__ __align__(16) unsigned short As[64 * 64];   //  8 KB
    __shared__ __align__(16) unsigned short Bs[128 * 64];  // 16 KB
    int tid = threadIdx.x;
    int wave = tid >> 6, lane = tid & 63;
    int quad = lane >> 4, l16 = lane & 15;
    int wr = wave >> 1, wc = wave & 1;
    int g = blockIdx.x;
    int tle = (g & 7) * 32 + (g >> 3);
    int mt = tle >> 2, nt = tle & 3;
    int m0 = mt * 64, n0 = nt * 128;

    const unsigned short* ag[2]; unsigned short* la[2];
    const unsigned short* bg[4]; unsigned short* lb[4];
#pragma unroll
    for (int i = 0; i < 2; ++i) {
        int gg = (wave * 2 + i) * 64 + lane;
        int r = gg >> 3, c = gg & 7, cs = c ^ (r & 7);
        int am = m0 + r;
        ag[i] = Xb + ((size_t)(am >> 7) * LL + (am & 127)) * H + cs * 8;
        la[i] = As + (wave * 2 + i) * 512;
    }
#pragma unroll
    for (int i = 0; i < 4; ++i) {
        int gg = (wave * 4 + i) * 64 + lane;
        int r = gg >> 3, c = gg & 7, cs = c ^ (r & 7);
        bg[i] = Uwb + (size_t)(n0 + r) * H + cs * 8;
        lb[i] = Bs + (wave * 4 + i) * 512;
    }

    f32x4 acc[2][4] = {};
    for (int k0 = 0; k0 < H; k0 += 64) {
#pragma unroll
        for (int i = 0; i < 2; ++i) gload16(ag[i] + k0, la[i]);
#pragma unroll
        for (int i = 0; i < 4; ++i) gload16(bg[i] + k0, lb[i]);
        __syncthreads();
#pragma unroll
        for (int kh = 0; kh < 2; ++kh) {
            s16x8 af[2], bfr[4];
#pragma unroll
            for (int mi = 0; mi < 2; ++mi) {
                int row = wr * 32 + mi * 16 + l16;
                int ch = (kh * 4 + quad) ^ (row & 7);
                af[mi] = *(const s16x8*)&As[(row * 8 + ch) * 8];
            }
#pragma unroll
            for (int ni = 0; ni < 4; ++ni) {
                int row = wc * 64 + ni * 16 + l16;
                int ch = (kh * 4 + quad) ^ (row & 7);
                bfr[ni] = *(const s16x8*)&Bs[(row * 8 + ch) * 8];
            }
#pragma unroll
            for (int mi = 0; mi < 2; ++mi)
#pragma unroll
                for (int ni = 0; ni < 4; ++ni)
                    acc[mi][ni] = __builtin_amdgcn_mfma_f32_16x16x32_bf16(
                        af[mi], bfr[ni], acc[mi][ni], 0, 0, 0);
        }
        __syncthreads();
    }
#pragma unroll
    for (int mi = 0; mi < 2; ++mi)
#pragma unroll
        for (int ni = 0; ni < 4; ++ni)
#pragma unroll
            for (int i = 0; i < 4; ++i) {
                int row = m0 + wr * 32 + mi * 16 + quad * 4 + i;
                int col = n0 + wc * 64 + ni * 16 + l16;
                hqU[(size_t)row * H + col] = f2bf(acc[mi][ni][i]);
            }
}

// ---------------------------------------------------------------- K2: score maxes
// 64(q) x 256(r) tiles, BK=64. grid 512 = (b,k,qt), XCD-swizzled. maxq complete,
// maxr partial over qt.
__global__ __launch_bounds__(256) void k2_scores(
    const unsigned short* __restrict__ hqU, const unsigned short* __restrict__ Xb,
    float* __restrict__ maxq, float* __restrict__ maxr_part) {
    __shared__ __align__(16) unsigned short As[64 * 64];   //  8 KB
    __shared__ __align__(16) unsigned short Bs[256 * 64];  // 32 KB
    __shared__ float redA[64 * 2];
    __shared__ float redB[256 * 2];
    int g = blockIdx.x;
    int tle = (g & 7) * 64 + (g >> 3);
    int qt = tle & 1, k = (tle >> 1) & 7, b = tle >> 4;
    int tid = threadIdx.x;
    int wave = tid >> 6, lane = tid & 63;
    int quad = lane >> 4, l16 = lane & 15;
    int wr = wave >> 1, wc = wave & 1;

    const unsigned short* Ab = hqU + (size_t)(b * LQ + qt * 64) * H;
    const unsigned short* Bb = Xb + (size_t)(b * LL + LQ + k * LR) * H;

    const unsigned short* ag[2]; unsigned short* la[2];
    const unsigned short* bg[8]; unsigned short* lb[8];
#pragma unroll
    for (int i = 0; i < 2; ++i) {
        int gg = (wave * 2 + i) * 64 + lane;
        int r = gg >> 3, c = gg & 7, cs = c ^ (r & 7);
        ag[i] = Ab + (size_t)r * H + cs * 8;
        la[i] = As + (wave * 2 + i) * 512;
    }
#pragma unroll
    for (int i = 0; i < 8; ++i) {
        int gg = (wave * 8 + i) * 64 + lane;
        int r = gg >> 3, c = gg & 7, cs = c ^ (r & 7);
        bg[i] = Bb + (size_t)r * H + cs * 8;
        lb[i] = Bs + (wave * 8 + i) * 512;
    }

    f32x4 acc[2][8] = {};
    for (int k0 = 0; k0 < H; k0 += 64) {
#pragma unroll
        for (int i = 0; i < 2; ++i) gload16(ag[i] + k0, la[i]);
#pragma unroll
        for (int i = 0; i < 8; ++i) gload16(bg[i] + k0, lb[i]);
        __syncthreads();
#pragma unroll
        for (int kh = 0; kh < 2; ++kh) {
            s16x8 af[2], bfr[8];
#pragma unroll
            for (int mi = 0; mi < 2; ++mi) {
                int row = wr * 32 + mi * 16 + l16;
                int ch = (kh * 4 + quad) ^ (row & 7);
                af[mi] = *(const s16x8*)&As[(row * 8 + ch) * 8];
            }
#pragma unroll
            for (int ni = 0; ni < 8; ++ni) {
                int row = wc * 128 + ni * 16 + l16;
                int ch = (kh * 4 + quad) ^ (row & 7);
                bfr[ni] = *(const s16x8*)&Bs[(row * 8 + ch) * 8];
            }
#pragma unroll
            for (int mi = 0; mi < 2; ++mi)
#pragma unroll
                for (int ni = 0; ni < 8; ++ni)
                    acc[mi][ni] = __builtin_amdgcn_mfma_f32_16x16x32_bf16(
                        af[mi], bfr[ni], acc[mi][ni], 0, 0, 0);
        }
        __syncthreads();
    }
#pragma unroll
    for (int mi = 0; mi < 2; ++mi)
#pragma unroll
        for (int i = 0; i < 4; ++i) {
            float v = acc[mi][0][i];
#pragma unroll
            for (int ni = 1; ni < 8; ++ni) v = fmaxf(v, acc[mi][ni][i]);
            for (int s = 1; s < 16; s <<= 1) v = fmaxf(v, __shfl_xor(v, s));
            if (l16 == 0) redA[(wr * 32 + mi * 16 + quad * 4 + i) * 2 + wc] = v;
        }
#pragma unroll
    for (int ni = 0; ni < 8; ++ni) {
        float v = acc[0][ni][0];
#pragma unroll
        for (int mi = 0; mi < 2; ++mi)
#pragma unroll
            for (int i = 0; i < 4; ++i) v = fmaxf(v, acc[mi][ni][i]);
        for (int s = 16; s < 64; s <<= 1) v = fmaxf(v, __shfl_xor(v, s));
        if (quad == 0) redB[(wc * 128 + ni * 16 + l16) * 2 + wr] = v;
    }
    __syncthreads();
    size_t bk = (size_t)(b * KK + k);
    if (tid < 64)
        maxq[bk * 128 + qt * 64 + tid] = fmaxf(redA[tid * 2 + 0], redA[tid * 2 + 1]);
    maxr_part[(bk * 2 + qt) * 256 + tid] = fmaxf(redB[tid * 2 + 0], redB[tid * 2 + 1]);
}

// ---------------------------------------------------------------- K3: alphas + wq (grid B*KK)
__global__ __launch_bounds__(256) void k3_alphas(
    const float* __restrict__ maxq, const float* __restrict__ maxr_part,
    const float* __restrict__ r_mask, const float* __restrict__ q_mask,
    float* __restrict__ wbuf) {
    int b = blockIdx.x >> 3, k = blockIdx.x & 7;
    int t = threadIdx.x;
    __shared__ float red[256];
    size_t bk = (size_t)(b * KK + k);
    float vq = -1e30f;
    if (t < 128) vq = fast_tanh(maxq[bk * 128 + t]);
    red[t] = vq; __syncthreads();
    for (int s = 128; s > 0; s >>= 1) { if (t < s) red[t] = fmaxf(red[t], red[t + s]); __syncthreads(); }
    float mxq = red[0]; __syncthreads();
    float eq = (t < 128) ? fexp2((vq - mxq) * LOG2E) : 0.f;
    red[t] = eq; __syncthreads();
    for (int s = 128; s > 0; s >>= 1) { if (t < s) red[t] += red[t + s]; __syncthreads(); }
    float invq = 1.f / red[0]; __syncthreads();
    if (t < 128)
        atomicAdd(&wbuf[b * LL + t], q_mask[b * LQ + t] * eq * invq * 0.125f);
    float vr = fast_tanh(fmaxf(maxr_part[(bk * 2 + 0) * 256 + t],
                               maxr_part[(bk * 2 + 1) * 256 + t]));
    red[t] = vr; __syncthreads();
    for (int s = 128; s > 0; s >>= 1) { if (t < s) red[t] = fmaxf(red[t], red[t + s]); __syncthreads(); }
    float mxr = red[0]; __syncthreads();
    float er = fexp2((vr - mxr) * LOG2E);
    red[t] = er; __syncthreads();
    for (int s = 128; s > 0; s >>= 1) { if (t < s) red[t] += red[t + s]; __syncthreads(); }
    float invr = 1.f / red[0];
    wbuf[b * LL + LQ + k * LR + t] = r_mask[bk * LR + t] * er * invr;
}

// ---------------------------------------------------------------- K4: big GEMM + fused logits
// 128x128 tile, BK=64; grid 2176 = 544 mt x 4 nt, XCD-swizzled (4 nt consecutive).
__global__ __launch_bounds__(256) void k4_gemm_logits(
    const unsigned short* __restrict__ Xb, const unsigned short* __restrict__ Wqrb,
    const float* __restrict__ sWs, const float* __restrict__ Wqr_b,
    const float* __restrict__ Wc_w, const float* __restrict__ Vr_w,
    const float* __restrict__ wbuf, const float* __restrict__ qr_cov,
    float* __restrict__ logits) {
    __shared__ __align__(16) unsigned short As[128 * 64];  // 16 KB
    __shared__ __align__(16) unsigned short Bs[128 * 64];  // 16 KB
    __shared__ float wrow[128], covrow[128], sWsl[128], biasl[128], wcl[128], vrl[128];
    int tid = threadIdx.x;
    int wave = tid >> 6, lane = tid & 63;
    int quad = lane >> 4, l16 = lane & 15;
    int wr = wave >> 1, wc = wave & 1;
    int g = blockIdx.x;
    int tle = (g & 7) * 272 + (g >> 3);
    int mt = tle >> 2, nt = tle & 3;
    size_t m0 = (size_t)mt * 128;     // never crosses batch: LL = 17*128
    int n0 = nt * 128;
    int b = mt / 17;

    if (tid < 128) {
        wrow[tid]   = wbuf[m0 + tid];
        covrow[tid] = qr_cov[m0 + tid];
        sWsl[tid]   = sWs[b * H + n0 + tid];
        biasl[tid]  = Wqr_b[n0 + tid];
        wcl[tid]    = Wc_w[n0 + tid];
        vrl[tid]    = Vr_w[n0 + tid];
    }

    const unsigned short* ag[4]; unsigned short* la[4];
    const unsigned short* bg[4]; unsigned short* lb[4];
#pragma unroll
    for (int i = 0; i < 4; ++i) {
        int gg = (wave * 4 + i) * 64 + lane;
        int r = gg >> 3, c = gg & 7, cs = c ^ (r & 7);
        ag[i] = Xb + (m0 + r) * H + cs * 8;
        bg[i] = Wqrb + (size_t)(n0 + r) * H + cs * 8;
        la[i] = As + (wave * 4 + i) * 512;
        lb[i] = Bs + (wave * 4 + i) * 512;
    }

    f32x4 acc[4][4] = {};
    for (int k0 = 0; k0 < H; k0 += 64) {
#pragma unroll
        for (int i = 0; i < 4; ++i) gload16(ag[i] + k0, la[i]);
#pragma unroll
        for (int i = 0; i < 4; ++i) gload16(bg[i] + k0, lb[i]);
        __syncthreads();
#pragma unroll
        for (int kh = 0; kh < 2; ++kh) {
            s16x8 af[4], bfr[4];
#pragma unroll
            for (int mi = 0; mi < 4; ++mi) {
                int row = wr * 64 + mi * 16 + l16;
                int ch = (kh * 4 + quad) ^ (row & 7);
                af[mi] = *(const s16x8*)&As[(row * 8 + ch) * 8];
            }
#pragma unroll
            for (int ni = 0; ni < 4; ++ni) {
                int row = wc * 64 + ni * 16 + l16;
                int ch = (kh * 4 + quad) ^ (row & 7);
                bfr[ni] = *(const s16x8*)&Bs[(row * 8 + ch) * 8];
            }
#pragma unroll
            for (int mi = 0; mi < 4; ++mi)
#pragma unroll
                for (int ni = 0; ni < 4; ++ni)
                    acc[mi][ni] = __builtin_amdgcn_mfma_f32_16x16x32_bf16(
                        af[mi], bfr[ni], acc[mi][ni], 0, 0, 0);
        }
        __syncthreads();
    }
#pragma unroll
    for (int mi = 0; mi < 4; ++mi)
#pragma unroll
        for (int i = 0; i < 4; ++i) {
            int rl = wr * 64 + mi * 16 + quad * 4 + i;
            float wv = wrow[rl], cv = covrow[rl];
            float lsum = 0.f;
#pragma unroll
            for (int ni = 0; ni < 4; ++ni) {
                int ol = wc * 64 + ni * 16 + l16;
                float dec = sWsl[ol] + wv * acc[mi][ni][i] + biasl[ol] + cv * wcl[ol];
                lsum += vrl[ol] * fast_tanh(dec);
            }
            for (int s = 1; s < 16; s <<= 1) lsum += __shfl_xor(lsum, s);
            if (l16 == 0) atomicAdd(&logits[m0 + rl], lsum);
        }
}

// ---------------------------------------------------------------- K5a: softmax -> a, new_cov, coef
__global__ __launch_bounds__(256) void k5a_softmax(
    const float* __restrict__ logits, const float* __restrict__ q_mask,
    const float* __restrict__ r_mask, const float* __restrict__ qr_cov,
    const float* __restrict__ wbuf, float* __restrict__ out,
    float* __restrict__ coef) {
    int b = blockIdx.x, t = threadIdx.x;
    __shared__ float lg[LL];
    __shared__ float red[256];
    float mx = -1e30f;
    for (int l = t; l < LL; l += 256) {
        float v = logits[b * LL + l];
        lg[l] = v;
        mx = fmaxf(mx, v);
    }
    red[t] = mx; __syncthreads();
    for (int s = 128; s > 0; s >>= 1) { if (t < s) red[t] = fmaxf(red[t], red[t + s]); __syncthreads(); }
    mx = red[0]; __syncthreads();
    float sum = 0.f;
    for (int l = t; l < LL; l += 256) {
        float e = fexp2((lg[l] - mx) * LOG2E);
        float m = (l < LQ) ? q_mask[b * LQ + l] : r_mask[b * (KK * LR) + l - LQ];
        float em = e * m;
        lg[l] = em;
        sum += em;
    }
    red[t] = sum; __syncthreads();
    for (int s = 128; s > 0; s >>= 1) { if (t < s) red[t] += red[t + s]; __syncthreads(); }
    float inv = 1.f / red[0];
    __syncthreads();
    float* aout = out + B * H + (size_t)b * LL;
    float* cov  = out + B * H + (size_t)B * LL + (size_t)b * LL;
    for (int l = t; l < LL; l += 256) {
        float a = lg[l] * inv;
        aout[l] = a;
        cov[l] = qr_cov[b * LL + l] + a;
        coef[b * LL + l] = a * wbuf[b * LL + l];
    }
}

// ---------------------------------------------------------------- K5b: c_t = sum_l coef_l * X_l
__global__ __launch_bounds__(256) void k5b_ct(
    const unsigned short* __restrict__ Xb, const float* __restrict__ coef,
    float* __restrict__ out) {
    int b = blockIdx.x / 17, chunk = blockIdx.x % 17;
    int t = threadIdx.x;
    int l0 = chunk * 128;
    __shared__ float cl[128];
    __shared__ float red[4][512];
    if (t < 128) cl[t] = coef[b * LL + l0 + t];
    __syncthreads();
    int rr = t >> 6, lane = t & 63, cc = lane * 8;
    float a[8] = {};
    const unsigned short* xp = Xb + ((size_t)b * LL + l0) * H;
    for (int l = rr; l < 128; l += 4) {
        float c = cl[l];
        uint4 u4 = *(const uint4*)(xp + (size_t)l * H + cc);
        a[0] += c * __uint_as_float(u4.x << 16);
        a[1] += c * __uint_as_float(u4.x & 0xffff0000u);
        a[2] += c * __uint_as_float(u4.y << 16);
        a[3] += c * __uint_as_float(u4.y & 0xffff0000u);
        a[4] += c * __uint_as_float(u4.z << 16);
        a[5] += c * __uint_as_float(u4.z & 0xffff0000u);
        a[6] += c * __uint_as_float(u4.w << 16);
        a[7] += c * __uint_as_float(u4.w & 0xffff0000u);
    }
#pragma unroll
    for (int j = 0; j < 8; ++j) red[rr][cc + j] = a[j];
    __syncthreads();
    int col = t * 2;
    float s0 = red[0][col] + red[1][col] + red[2][col] + red[3][col];
    float s1 = red[0][col + 1] + red[1][col + 1] + red[2][col + 1] + red[3][col + 1];
    atomicAdd(&out[b * H + col], s0);
    atomicAdd(&out[b * H + col + 1], s1);
}

// ================================================================ launch
extern "C" void kernel_launch(void* const* d_in, const int* in_sizes, int n_in,
                              void* d_out, int out_size, void* d_ws, size_t ws_size,
                              hipStream_t stream) {
    (void)in_sizes; (void)n_in; (void)out_size; (void)ws_size;
    const float* h_q    = (const float*)d_in[0];
    const float* q_mask = (const float*)d_in[1];
    const float* h_r    = (const float*)d_in[2];
    const float* r_mask = (const float*)d_in[3];
    const float* s_t    = (const float*)d_in[4];
    const float* qr_cov = (const float*)d_in[5];
    const float* U_w    = (const float*)d_in[6];
    const float* Wc_w   = (const float*)d_in[7];
    const float* Ws_w   = (const float*)d_in[8];
    const float* Wqr_w  = (const float*)d_in[9];
    const float* Wqr_b  = (const float*)d_in[10];
    const float* Vr_w   = (const float*)d_in[11];
    float* out = (float*)d_out;

    char* p = (char*)d_ws;
    unsigned short* Xb   = (unsigned short*)p; p += (size_t)B * LL * H * 2;
    unsigned short* Uwb  = (unsigned short*)p; p += (size_t)H * H * 2;
    unsigned short* Wqrb = (unsigned short*)p; p += (size_t)H * H * 2;
    unsigned short* hqU  = (unsigned short*)p; p += (size_t)B * LQ * H * 2;
    float* sWs       = (float*)p; p += (size_t)B * H * 4;
    float* maxq      = (float*)p; p += (size_t)B * KK * 128 * 4;
    float* maxr_part = (float*)p; p += (size_t)B * KK * 2 * 256 * 4;
    float* wbuf      = (float*)p; p += (size_t)B * LL * 4;
    float* logits    = (float*)p; p += (size_t)B * LL * 4;
    float* coef      = (float*)p; p += (size_t)B * LL * 4;

    k0_convert<<<K0GRID, 256, 0, stream>>>(h_q, h_r, U_w, Wqr_w, Xb, Uwb, Wqrb,
                                           logits, out, wbuf, s_t, Ws_w, sWs);
    k1_gemm_hqU<<<256, 256, 0, stream>>>(Xb, Uwb, hqU);
    k2_scores<<<512, 256, 0, stream>>>(hqU, Xb, maxq, maxr_part);
    k3_alphas<<<B * KK, 256, 0, stream>>>(maxq, maxr_part, r_mask, q_mask, wbuf);
    k4_gemm_logits<<<2176, 256, 0, stream>>>(
        Xb, Wqrb, sWs, Wqr_b, Wc_w, Vr_w, wbuf, qr_cov, logits);
    k5a_softmax<<<B, 256, 0, stream>>>(logits, q_mask, r_mask, qr_cov, wbuf, out, coef);
    k5b_ct<<<B * (LL / 128), 256, 0, stream>>>(Xb, coef, out);
}